// Round 2
// baseline (109.916 us; speedup 1.0000x reference)
//
#include <hip/hip_runtime.h>

// Shapes (fixed by setup_inputs)
constexpr int N  = 4, C = 64, H = 16, W = 16;
constexpr int NF = 128;
constexpr int D  = C * 9;          // 576
constexpr float EPSF = 1e-5f;

// ---------------------------------------------------------------------------
// Prep: w_t[k][f] = w[f][k]  (for K1, coalesced over f)
//       w2f[(f*9 + a*3 + b)*64 + c] = w[f][c*9 + (2-a)*3 + (2-b)]  (for K2,
//       pre-flipped so K2's inner loop indexes (a,b) directly, coalesced c)
// ---------------------------------------------------------------------------
__global__ void k_prep(const float* __restrict__ w,
                       float* __restrict__ w_t, float* __restrict__ w2f) {
    int gid = blockIdx.x * blockDim.x + threadIdx.x;
    if (gid < D * NF) {
        int k = gid / NF, f = gid % NF;
        w_t[gid] = w[f * D + k];
    } else {
        int g = gid - D * NF;
        if (g < NF * 9 * C) {
            int c = g % C;
            int t = g / C;              // f*9 + a*3 + b
            int ab = t % 9, f = t / 9;
            int a = ab / 3, b = ab % 3;
            int kap = (2 - a) * 3 + (2 - b);
            w2f[g] = w[f * D + c * 9 + kap];
        }
    }
}

// ---------------------------------------------------------------------------
// K1: s[n,f,oh,ow] = conv3x3(x, w) in fp64;  t = 2r/(2s+eps)
// Grid: 256 blocks = (n, oh, ow-quarter).  Threads: 256 = (f 128) x (cg 2).
// cg splits the c-reduction in half; halves combined through LDS.
// x neighborhood (64ch x 3 x 6, fp64) staged in LDS; w_t rows streamed from
// L2, coalesced over f-lanes.
// ---------------------------------------------------------------------------
__global__ void __launch_bounds__(256) k_conv_t(
        const float* __restrict__ x, const float* __restrict__ w_t,
        const float* __restrict__ r, float* __restrict__ t_g) {
    __shared__ double xl[C * 18];          // [c][dh*6+dw], 9.2 KB
    __shared__ double part[4][NF];         // cg=1 partials, 4 KB

    const int pg  = blockIdx.x;            // (n, oh, ow0/4)
    const int ow0 = (pg & 3) * 4;
    const int oh  = (pg >> 2) & 15;
    const int n   = pg >> 6;
    const int tid = threadIdx.x;
    const int f   = tid & 127;
    const int cg  = tid >> 7;              // 0 or 1

    // stage x: xl[c][dh*6+dw] = x[n,c,oh-1+dh,ow0-1+dw] (zero-padded)
    for (int idx = tid; idx < C * 18; idx += 256) {
        int c = idx / 18, rem = idx % 18;
        int dh = rem / 6, dw = rem % 6;
        int ih = oh - 1 + dh, iw = ow0 - 1 + dw;
        float v = 0.f;
        if (ih >= 0 && ih < H && iw >= 0 && iw < W)
            v = x[((n * C + c) * H + ih) * W + iw];
        xl[idx] = (double)v;
    }
    __syncthreads();

    double a0 = 0, a1 = 0, a2 = 0, a3 = 0;
    const int c_lo = cg * 32, c_hi = c_lo + 32;
    const float* wp = w_t + f;
    int k = c_lo * 9;
    for (int c = c_lo; c < c_hi; ++c) {
        const double* xc = xl + c * 18;
#pragma unroll
        for (int kap = 0; kap < 9; ++kap, ++k) {
            double wd = (double)wp[k * NF];
            const double* xv = xc + (kap / 3) * 6 + (kap % 3);
            a0 += wd * xv[0];
            a1 += wd * xv[1];
            a2 += wd * xv[2];
            a3 += wd * xv[3];
        }
    }

    if (cg == 1) {
        part[0][f] = a0; part[1][f] = a1; part[2][f] = a2; part[3][f] = a3;
    }
    __syncthreads();
    if (cg == 0) {
        a0 += part[0][f]; a1 += part[1][f]; a2 += part[2][f]; a3 += part[3][f];
        const int base = ((n * NF + f) * H + oh) * W + ow0;   // r and t share layout
        const float* rp = r + base;
        float* tp = t_g + base;
        tp[0] = (float)((2.0 * (double)rp[0]) / (2.0 * a0 + (double)EPSF));
        tp[1] = (float)((2.0 * (double)rp[1]) / (2.0 * a1 + (double)EPSF));
        tp[2] = (float)((2.0 * (double)rp[2]) / (2.0 * a2 + (double)EPSF));
        tp[3] = (float)((2.0 * (double)rp[3]) / (2.0 * a3 + (double)EPSF));
    }
}

// ---------------------------------------------------------------------------
// K2: out[n,c,h,w] = x[n,c,h,w] * sum_{f,a,b} w2f[f,a,b,c] * t[n,f,h-1+a,w-1+b]
// Grid: 256 blocks = (n, h, c-slice of 16).  Threads: 128 = (w 16) x (cl 8),
// each thread owns 2 consecutive channels (w2f pair -> dwordx2).
// t slab (128f x 3 rows, ow-padded to 18) staged in LDS: 27.6 KB.
// ---------------------------------------------------------------------------
__global__ void __launch_bounds__(128) k_convT_out(
        const float* __restrict__ x, const float* __restrict__ w2f,
        const float* __restrict__ t_g, float* __restrict__ out) {
    __shared__ float tl[NF * 54];          // [f][a][ww], ww = ow+1, 27.6 KB

    const int bid = blockIdx.x;
    const int cs  = bid & 3;
    const int h   = (bid >> 2) & 15;
    const int n   = bid >> 6;
    const int tid = threadIdx.x;

    // stage t: tl[f*54 + a*18 + ww] = t[n,f,h-1+a,ww-1] (zero-padded)
    for (int idx = tid; idx < NF * 54; idx += 128) {
        int f = idx / 54, rem = idx % 54;
        int a = rem / 18, ww = rem % 18;
        int ohh = h - 1 + a, ow = ww - 1;
        float v = 0.f;
        if (ohh >= 0 && ohh < H && ow >= 0 && ow < W)
            v = t_g[((n * NF + f) * H + ohh) * W + ow];
        tl[idx] = v;
    }
    __syncthreads();

    const int wl = tid & 15;
    const int cl = tid >> 4;               // 0..7
    const int c0 = cs * 16 + cl * 2;

    float acc0 = 0.f, acc1 = 0.f;
#pragma unroll 4
    for (int f = 0; f < NF; ++f) {
        const float* tf = tl + f * 54 + wl;
        const float* wf = w2f + (f * 9) * C + c0;
#pragma unroll
        for (int a = 0; a < 3; ++a) {
#pragma unroll
            for (int b = 0; b < 3; ++b) {
                float tv = tf[a * 18 + b];
                const float* wv = wf + (a * 3 + b) * C;
                acc0 += tv * wv[0];
                acc1 += tv * wv[1];
            }
        }
    }

    const int o0 = ((n * C + c0) * H + h) * W + wl;
    out[o0]       = x[o0]       * acc0;
    out[o0 + 256] = x[o0 + 256] * acc1;    // c0+1 -> +H*W
}

// ---------------------------------------------------------------------------
extern "C" void kernel_launch(void* const* d_in, const int* in_sizes, int n_in,
                              void* d_out, int out_size, void* d_ws, size_t ws_size,
                              hipStream_t stream) {
    const float* x = (const float*)d_in[0];   // (4,64,16,16)
    const float* r = (const float*)d_in[1];   // (4,128,16,16)
    const float* w = (const float*)d_in[2];   // (128,64,3,3)
    float* out = (float*)d_out;               // (4,64,16,16)

    float* ws   = (float*)d_ws;
    float* w_t  = ws;                         // D*NF   = 73728
    float* w2f  = w_t + D * NF;               // NF*9*C = 73728
    float* t_g  = w2f + NF * 9 * C;           // N*NF*H*W = 131072

    k_prep<<<(2 * D * NF) / 256, 256, 0, stream>>>(w, w_t, w2f);
    k_conv_t<<<256, 256, 0, stream>>>(x, w_t, r, t_g);
    k_convT_out<<<256, 128, 0, stream>>>(x, w2f, t_g, out);
}

// Round 3
// 85.994 us; speedup vs baseline: 1.2782x; 1.2782x over previous
//
#include <hip/hip_runtime.h>

// Shapes (fixed by setup_inputs)
constexpr int N  = 4, C = 64, H = 16, W = 16;
constexpr int NF = 128;
constexpr int D  = C * 9;          // 576
constexpr float EPSF = 1e-5f;

// ---------------------------------------------------------------------------
// Prep: w_t[k][f] = w[f][k]                          (K1, coalesced over f)
//       w2f[(f*9 + a*3 + b)*C + c] = w[f][c*9 + (2-a)*3 + (2-b)]
//                                                    (K2, flipped, coalesced c)
// ---------------------------------------------------------------------------
__global__ void k_prep(const float* __restrict__ w,
                       float* __restrict__ w_t, float* __restrict__ w2f) {
    int gid = blockIdx.x * blockDim.x + threadIdx.x;
    if (gid < D * NF) {
        int k = gid / NF, f = gid % NF;
        w_t[gid] = w[f * D + k];
    } else {
        int g = gid - D * NF;
        if (g < NF * 9 * C) {
            int c = g % C;
            int t = g / C;              // f*9 + a*3 + b
            int ab = t % 9, f = t / 9;
            int a = ab / 3, b = ab % 3;
            w2f[g] = w[f * D + c * 9 + (2 - a) * 3 + (2 - b)];
        }
    }
}

// ---------------------------------------------------------------------------
// K1: s = conv3x3(x,w) in fp64; t = 2r/(2s+eps)
// Grid 256 = (n, oh, ow-quarter). Threads 512 = (f 128) x (cg 4, c-split 16).
// x rows are block-uniform -> scalar loads; w_t coalesced over f-lanes.
// 6-wide x row reused across 3 taps x 4 outputs (12 f64 FMA / row).
// ---------------------------------------------------------------------------
__global__ void __launch_bounds__(512) k_conv_t(
        const float* __restrict__ x, const float* __restrict__ w_t,
        const float* __restrict__ r, float* __restrict__ t_g) {
    __shared__ double part[3][NF][4];      // 12 KB, cg=1..3 partials

    const int bid = blockIdx.x;
    const int ow0 = (bid & 3) * 4;
    const int oh  = (bid >> 2) & 15;
    const int n   = bid >> 6;
    const int tid = threadIdx.x;
    const int f   = tid & 127;
    const int cg  = tid >> 7;              // 0..3
    const int iw0 = ow0 - 1;

    double a0 = 0, a1 = 0, a2 = 0, a3 = 0;
    const float* __restrict__ wp = w_t + f;

    for (int ci = 0; ci < 16; ++ci) {
        const int c = cg * 16 + ci;
        const float* xbase = x + ((n * C + c) * H) * W;
#pragma unroll
        for (int dh = 0; dh < 3; ++dh) {
            const int ih = oh - 1 + dh;
            float xr[6];
            if (ih >= 0 && ih < H) {
                const float* xrow = xbase + ih * W;
#pragma unroll
                for (int j = 0; j < 6; ++j) {
                    int iw = iw0 + j;
                    xr[j] = (iw >= 0 && iw < W) ? xrow[iw] : 0.f;
                }
            } else {
#pragma unroll
                for (int j = 0; j < 6; ++j) xr[j] = 0.f;
            }
            double xd[6];
#pragma unroll
            for (int j = 0; j < 6; ++j) xd[j] = (double)xr[j];
            const int kbase = (c * 9 + dh * 3) * NF;
#pragma unroll
            for (int b = 0; b < 3; ++b) {
                double wd = (double)wp[kbase + b * NF];
                a0 += wd * xd[b];
                a1 += wd * xd[b + 1];
                a2 += wd * xd[b + 2];
                a3 += wd * xd[b + 3];
            }
        }
    }

    if (cg > 0) {
        part[cg - 1][f][0] = a0; part[cg - 1][f][1] = a1;
        part[cg - 1][f][2] = a2; part[cg - 1][f][3] = a3;
    }
    __syncthreads();
    if (cg == 0) {
#pragma unroll
        for (int g = 0; g < 3; ++g) {
            a0 += part[g][f][0]; a1 += part[g][f][1];
            a2 += part[g][f][2]; a3 += part[g][f][3];
        }
        const int base = ((n * NF + f) * H + oh) * W + ow0;
        const float* rp = r + base;
        float* tp = t_g + base;
        tp[0] = (float)((2.0 * (double)rp[0]) / (2.0 * a0 + (double)EPSF));
        tp[1] = (float)((2.0 * (double)rp[1]) / (2.0 * a1 + (double)EPSF));
        tp[2] = (float)((2.0 * (double)rp[2]) / (2.0 * a2 + (double)EPSF));
        tp[3] = (float)((2.0 * (double)rp[3]) / (2.0 * a3 + (double)EPSF));
    }
}

// ---------------------------------------------------------------------------
// K2: out[n,c,h,w] = x[n,c,h,w] * sum_{f,a,b} w2f[f,a,b,c]*t[n,f,h-1+a,w-1+b]
// Grid 256 = (n, h, w-quarter). Threads 512 = (c 64) x (fg 8, f-split 16).
// t rows are block-uniform -> scalar loads; w2f coalesced over c-lanes.
// ---------------------------------------------------------------------------
__global__ void __launch_bounds__(512) k_convT_out(
        const float* __restrict__ x, const float* __restrict__ w2f,
        const float* __restrict__ t_g, float* __restrict__ out) {
    __shared__ float part[7][C][4];        // 7 KB, fg=1..7 partials

    const int bid = blockIdx.x;
    const int w0  = (bid & 3) * 4;
    const int h   = (bid >> 2) & 15;
    const int n   = bid >> 6;
    const int tid = threadIdx.x;
    const int c   = tid & 63;
    const int fg  = tid >> 6;              // 0..7
    const int iw0 = w0 - 1;

    float a0 = 0, a1 = 0, a2 = 0, a3 = 0;

    for (int fi = 0; fi < 16; ++fi) {
        const int f = fg * 16 + fi;
        const float* tbase = t_g + ((n * NF + f) * H) * W;
        const float* __restrict__ wfa = w2f + (f * 9) * C + c;
#pragma unroll
        for (int a = 0; a < 3; ++a) {
            const int oh2 = h - 1 + a;
            float tr[6];
            if (oh2 >= 0 && oh2 < H) {
                const float* trow = tbase + oh2 * W;
#pragma unroll
                for (int j = 0; j < 6; ++j) {
                    int ow = iw0 + j;
                    tr[j] = (ow >= 0 && ow < W) ? trow[ow] : 0.f;
                }
            } else {
#pragma unroll
                for (int j = 0; j < 6; ++j) tr[j] = 0.f;
            }
#pragma unroll
            for (int b = 0; b < 3; ++b) {
                float wv = wfa[(a * 3 + b) * C];
                a0 += wv * tr[b];
                a1 += wv * tr[b + 1];
                a2 += wv * tr[b + 2];
                a3 += wv * tr[b + 3];
            }
        }
    }

    if (fg > 0) {
        part[fg - 1][c][0] = a0; part[fg - 1][c][1] = a1;
        part[fg - 1][c][2] = a2; part[fg - 1][c][3] = a3;
    }
    __syncthreads();
    if (fg == 0) {
#pragma unroll
        for (int g = 0; g < 7; ++g) {
            a0 += part[g][c][0]; a1 += part[g][c][1];
            a2 += part[g][c][2]; a3 += part[g][c][3];
        }
        const int base = ((n * C + c) * H + h) * W + w0;
        out[base + 0] = x[base + 0] * a0;
        out[base + 1] = x[base + 1] * a1;
        out[base + 2] = x[base + 2] * a2;
        out[base + 3] = x[base + 3] * a3;
    }
}

// ---------------------------------------------------------------------------
extern "C" void kernel_launch(void* const* d_in, const int* in_sizes, int n_in,
                              void* d_out, int out_size, void* d_ws, size_t ws_size,
                              hipStream_t stream) {
    const float* x = (const float*)d_in[0];   // (4,64,16,16)
    const float* r = (const float*)d_in[1];   // (4,128,16,16)
    const float* w = (const float*)d_in[2];   // (128,64,3,3)
    float* out = (float*)d_out;               // (4,64,16,16)

    float* ws   = (float*)d_ws;
    float* w_t  = ws;                         // D*NF   = 73728
    float* w2f  = w_t + D * NF;               // NF*9*C = 73728
    float* t_g  = w2f + NF * 9 * C;           // N*NF*H*W = 131072

    k_prep<<<(2 * D * NF + 255) / 256, 256, 0, stream>>>(w, w_t, w2f);
    k_conv_t<<<256, 512, 0, stream>>>(x, w_t, r, t_g);
    k_convT_out<<<256, 512, 0, stream>>>(x, w2f, t_g, out);
}